// Round 4
// baseline (295.565 us; speedup 1.0000x reference)
//
#include <hip/hip_runtime.h>

// DropBlock + LIF forward, two kernels (bit-packed masks).
// x: [T*bs, C, H, W] = [160, 64, 64, 64] f32, mask_rand: [160, 64, 64] f32
// out: [160, 64, 64, 64] f32
//
// Stage 1 (bm_bits_kernel): per row (one wave each), dropblock row-mask as a
//   64-bit word: 7 clipped vertical loads/lane -> OR -> __ballot (vertical
//   dilate) -> bit smear +/-3 (horizontal dilate). Set bit = dropped.
//   Output: 10240 x uint64 = 80 KB in d_ws (L1/L2-resident for stage 2).
// Stage 2 (lif_kernel): linear-index streaming, exact grid, one 32 B-contig
//   chunk per thread per stream (2x float4 NT ops at +0/+16) -> 2 KB contig
//   per wave access. R1 lesson: grid-stride multiplied per-thread HBM
//   streams 10->40 and regressed; keep one idx per thread. NT hints kept
//   (R0 structure). R2/R3 benches were container-acquire infra failures,
//   not kernel verdicts (different sources failed identically; bounds
//   re-audited: max index 41,943,039 < 41,943,040). Resubmitting to measure.
//   u = (u>1 ? 0 : 0.5u) + x_t (bitwise equal to tau*u*(1-spike)+x),
//   o_t = (u>1 && !dropped) ? 1 : 0. Per-t mask is one 8 B load, 8 bits used
//   per thread (8 distinct words per wave -> L1-hot broadcast).

#define TSTEPS 5
#define BSZ 32
#define CHN 64
#define HH 64
#define WW 64

typedef float v4f __attribute__((ext_vector_type(4)));

__global__ __launch_bounds__(256) void bm_bits_kernel(const float* __restrict__ mr,
                                                      unsigned long long* __restrict__ bmbits) {
    // one wave (64 lanes) per row; 4 waves per block; rows = T*bs*HH = 10240
    const float GAMMA = (float)(0.1 / 49.0);  // matches JAX weak-type promotion
    int row = blockIdx.x * 4 + (threadIdx.x >> 6);  // [0, 10240)
    int lane = threadIdx.x & 63;                    // pixel w
    int h = row & (HH - 1);
    int n = row >> 6;  // plane id in [0, T*bs)

    const float* base = mr + (size_t)n * (HH * WW) + lane;
    bool drop = false;
#pragma unroll
    for (int dh = -3; dh <= 3; ++dh) {
        int hh = h + dh;
        if (hh >= 0 && hh < HH) drop = drop || (base[hh * WW] < GAMMA);
    }
    unsigned long long m = __ballot(drop);  // bit w = column drop (vertical done)
    unsigned long long s = m | (m << 1) | (m << 2) | (m << 3)
                             | (m >> 1) | (m >> 2) | (m >> 3);
    if (lane == 0) bmbits[row] = s;  // set bit => dropped => output 0
}

__global__ __launch_bounds__(256) void lif_kernel(const float* __restrict__ x,
                                                  const unsigned long long* __restrict__ bmbits,
                                                  float* __restrict__ o) {
    const int HW8 = HH * WW / 8;  // 512 8-float groups per plane
    int idx = blockIdx.x * blockDim.x + threadIdx.x;  // [0, BSZ*CHN*HW8) = [0, 1048576)
    int hw8 = idx & (HW8 - 1);
    int c = (idx >> 9) & (CHN - 1);
    int b = idx >> 15;
    if (b >= BSZ) return;

    int h = hw8 >> 3;          // row within plane (8 groups per row)
    int sh = (hw8 & 7) * 8;    // bit shift into the 64-bit row mask

    size_t xoff = (((size_t)b * CHN + c) * (size_t)(HH * WW)) + (size_t)hw8 * 8;
    const size_t XT = (size_t)BSZ * CHN * HH * WW;  // x/o time stride (floats)
    int mrow = b * HH + h;                          // + t*BSZ*HH per step
    const int MT = BSZ * HH;

    v4f ua = {0.f, 0.f, 0.f, 0.f};
    v4f ub = {0.f, 0.f, 0.f, 0.f};
#pragma unroll
    for (int t = 0; t < TSTEPS; ++t) {
        const float* xp = x + xoff + (size_t)t * XT;
        v4f xa = __builtin_nontemporal_load((const v4f*)xp);
        v4f xb = __builtin_nontemporal_load((const v4f*)(xp + 4));
        unsigned int byte = (unsigned int)((bmbits[mrow + t * MT] >> sh) & 0xFFull);
        v4f oa, ob;
#pragma unroll
        for (int j = 0; j < 4; ++j) {
            ua[j] = (ua[j] > 1.0f ? 0.0f : 0.5f * ua[j]) + xa[j];
            oa[j] = (ua[j] > 1.0f && !(byte & (1u << j))) ? 1.0f : 0.0f;
            ub[j] = (ub[j] > 1.0f ? 0.0f : 0.5f * ub[j]) + xb[j];
            ob[j] = (ub[j] > 1.0f && !(byte & (1u << (j + 4)))) ? 1.0f : 0.0f;
        }
        float* op = o + xoff + (size_t)t * XT;
        __builtin_nontemporal_store(oa, (v4f*)op);
        __builtin_nontemporal_store(ob, (v4f*)(op + 4));
    }
}

extern "C" void kernel_launch(void* const* d_in, const int* in_sizes, int n_in,
                              void* d_out, int out_size, void* d_ws, size_t ws_size,
                              hipStream_t stream) {
    const float* x = (const float*)d_in[0];
    const float* mask_rand = (const float*)d_in[1];
    float* out = (float*)d_out;
    unsigned long long* bmbits = (unsigned long long*)d_ws;  // 10240 * 8 B = 80 KB

    const int bm_rows = TSTEPS * BSZ * HH;              // 10240 rows (1 wave each)
    const int lif_threads = BSZ * CHN * (HH * WW / 8);  // 1,048,576

    bm_bits_kernel<<<bm_rows / 4, 256, 0, stream>>>(mask_rand, bmbits);
    lif_kernel<<<lif_threads / 256, 256, 0, stream>>>(x, bmbits, out);
}

// Round 5
// 288.850 us; speedup vs baseline: 1.0232x; 1.0232x over previous
//
#include <hip/hip_runtime.h>

// DropBlock + LIF forward, two kernels (R5: clean NT A/B — exact R0
// structure, ONLY change is plain loads/stores instead of nontemporal).
// x: [T*bs, C, H, W] = [160, 64, 64, 64] f32, mask_rand: [160, 64, 64] f32
// out: [160, 64, 64, 64] f32
//
// Scoreboard: R0 (NT,16B/thr,exact) 280.6 | R1 (plain,grid-stride) 295.1 |
// R4 (NT,32B/thr) 295.6. R4 lesson: per-INSTRUCTION wave contiguity is the
// variable (32B/thr makes each dwordx4 load stride-32 across lanes -> 2KB
// span, half-touched). R1 lesson: >10 streams/thread hurts. NT-vs-plain
// never isolated -> this round.
//
// Stage 1 (bm_bits_kernel): per row (one wave each), dropblock row-mask as a
//   64-bit word: 7 clipped vertical loads/lane -> OR -> __ballot (vertical
//   dilate) -> bit smear +/-3 (horizontal dilate). Set bit = dropped.
// Stage 2 (lif_kernel): linear-index float4 streaming, one idx per thread,
//   wave = 1KB solid per access. u = (u>1 ? 0 : 0.5u) + x_t (bitwise equal
//   to tau*u*(1-spike)+x), o_t = (u>1 && !dropped) ? 1 : 0.

#define TSTEPS 5
#define BSZ 32
#define CHN 64
#define HH 64
#define WW 64

typedef float v4f __attribute__((ext_vector_type(4)));

__global__ __launch_bounds__(256) void bm_bits_kernel(const float* __restrict__ mr,
                                                      unsigned long long* __restrict__ bmbits) {
    // one wave (64 lanes) per row; 4 waves per block; rows = T*bs*HH = 10240
    const float GAMMA = (float)(0.1 / 49.0);  // matches JAX weak-type promotion
    int row = blockIdx.x * 4 + (threadIdx.x >> 6);  // [0, 10240)
    int lane = threadIdx.x & 63;                    // pixel w
    int h = row & (HH - 1);
    int n = row >> 6;  // plane id in [0, T*bs)

    const float* base = mr + (size_t)n * (HH * WW) + lane;
    bool drop = false;
#pragma unroll
    for (int dh = -3; dh <= 3; ++dh) {
        int hh = h + dh;
        if (hh >= 0 && hh < HH) drop = drop || (base[hh * WW] < GAMMA);
    }
    unsigned long long m = __ballot(drop);  // bit w = column drop (vertical done)
    unsigned long long s = m | (m << 1) | (m << 2) | (m << 3)
                             | (m >> 1) | (m >> 2) | (m >> 3);
    if (lane == 0) bmbits[row] = s;  // set bit => dropped => output 0
}

__global__ __launch_bounds__(256) void lif_kernel(const float* __restrict__ x,
                                                  const unsigned long long* __restrict__ bmbits,
                                                  float* __restrict__ o) {
    const int HW4 = HH * WW / 4;  // 1024 float4 groups per plane
    int idx = blockIdx.x * blockDim.x + threadIdx.x;  // [0, BSZ*CHN*HW4)
    int hw4 = idx & (HW4 - 1);
    int c = (idx >> 10) & (CHN - 1);
    int b = idx >> 16;
    if (b >= BSZ) return;

    int h = hw4 >> 4;     // row within plane
    int col4 = hw4 & 15;  // float4 column
    int sh = col4 * 4;

    size_t xoff = (((size_t)b * CHN + c) * (size_t)(HH * WW)) + (size_t)hw4 * 4;
    const size_t XT = (size_t)BSZ * CHN * HH * WW;  // x/o time stride
    int mrow = b * HH + h;                          // + t*BSZ*HH per step
    const int MT = BSZ * HH;

    v4f u = {0.f, 0.f, 0.f, 0.f};
#pragma unroll
    for (int t = 0; t < TSTEPS; ++t) {
        v4f xv = *(const v4f*)(x + xoff + (size_t)t * XT);
        unsigned int nib = (unsigned int)((bmbits[mrow + t * MT] >> sh) & 0xFull);
        u.x = (u.x > 1.0f ? 0.0f : 0.5f * u.x) + xv.x;
        u.y = (u.y > 1.0f ? 0.0f : 0.5f * u.y) + xv.y;
        u.z = (u.z > 1.0f ? 0.0f : 0.5f * u.z) + xv.z;
        u.w = (u.w > 1.0f ? 0.0f : 0.5f * u.w) + xv.w;
        v4f ov;
        ov.x = (u.x > 1.0f && !(nib & 1u)) ? 1.0f : 0.0f;
        ov.y = (u.y > 1.0f && !(nib & 2u)) ? 1.0f : 0.0f;
        ov.z = (u.z > 1.0f && !(nib & 4u)) ? 1.0f : 0.0f;
        ov.w = (u.w > 1.0f && !(nib & 8u)) ? 1.0f : 0.0f;
        *(v4f*)(o + xoff + (size_t)t * XT) = ov;
    }
}

extern "C" void kernel_launch(void* const* d_in, const int* in_sizes, int n_in,
                              void* d_out, int out_size, void* d_ws, size_t ws_size,
                              hipStream_t stream) {
    const float* x = (const float*)d_in[0];
    const float* mask_rand = (const float*)d_in[1];
    float* out = (float*)d_out;
    unsigned long long* bmbits = (unsigned long long*)d_ws;  // 10240 * 8 B = 80 KB

    const int bm_rows = TSTEPS * BSZ * HH;              // 10240 rows (1 wave each)
    const int lif_threads = BSZ * CHN * (HH * WW / 4);  // 2,097,152

    bm_bits_kernel<<<bm_rows / 4, 256, 0, stream>>>(mask_rand, bmbits);
    lif_kernel<<<(lif_threads + 255) / 256, 256, 0, stream>>>(x, bmbits, out);
}

// Round 8
// 278.010 us; speedup vs baseline: 1.0631x; 1.0390x over previous
//
#include <hip/hip_runtime.h>

// DropBlock + LIF forward, two kernels (R8 = R6/R7 resubmit; both prior
// attempts were container-acquire infra failures — R3/R4 proved identical
// sources can flake then pass; push-path timings in failing rounds show
// 971s/2616s npz-push stalls, i.e. failure upstream of kernel execution).
// NT + wave-chunk fattening: each thread owns TWO float4s one wave-chunk
// (1 KB) apart, so every load/store instruction still covers a solid 1 KB
// wave footprint.
// x: [T*bs, C, H, W] = [160, 64, 64, 64] f32, mask_rand: [160, 64, 64] f32
// out: [160, 64, 64, 64] f32
//
// Scoreboard: R0 (NT,16B/thr) 280.6 | R5 (plain,16B/thr) 288.9 -> NT wins.
// R4 (NT,32B/thr strided) 295.6 -> per-INSTRUCTION contiguity is what
// matters. R1 (grid-stride) 295.1 -> keep streams/thread minimal.
// R6-R8: fatten correctly: chunk0 = base+lane*16B, chunk1 = +1KB. Wave =
// 2 KB contiguous per t-stream; waves halve; 10 independent NT loads in
// flight per thread; mask/addr arithmetic amortized 2x.
//
// Stage 1 (bm_bits_kernel): per row (one wave each), dropblock row-mask as a
//   64-bit word: 7 clipped vertical loads/lane -> OR -> __ballot (vertical
//   dilate) -> bit smear +/-3 (horizontal dilate). Set bit = dropped.
// Stage 2 (lif_kernel): u = (u>1 ? 0 : 0.5u) + x_t (bitwise equal to
//   tau*u*(1-spike)+x), o_t = (u>1 && !dropped) ? 1 : 0.

#define TSTEPS 5
#define BSZ 32
#define CHN 64
#define HH 64
#define WW 64

typedef float v4f __attribute__((ext_vector_type(4)));

__global__ __launch_bounds__(256) void bm_bits_kernel(const float* __restrict__ mr,
                                                      unsigned long long* __restrict__ bmbits) {
    // one wave (64 lanes) per row; 4 waves per block; rows = T*bs*HH = 10240
    const float GAMMA = (float)(0.1 / 49.0);  // matches JAX weak-type promotion
    int row = blockIdx.x * 4 + (threadIdx.x >> 6);  // [0, 10240)
    int lane = threadIdx.x & 63;                    // pixel w
    int h = row & (HH - 1);
    int n = row >> 6;  // plane id in [0, T*bs)

    const float* base = mr + (size_t)n * (HH * WW) + lane;
    bool drop = false;
#pragma unroll
    for (int dh = -3; dh <= 3; ++dh) {
        int hh = h + dh;
        if (hh >= 0 && hh < HH) drop = drop || (base[hh * WW] < GAMMA);
    }
    unsigned long long m = __ballot(drop);  // bit w = column drop (vertical done)
    unsigned long long s = m | (m << 1) | (m << 2) | (m << 3)
                             | (m >> 1) | (m >> 2) | (m >> 3);
    if (lane == 0) bmbits[row] = s;  // set bit => dropped => output 0
}

__global__ __launch_bounds__(256) void lif_kernel(const float* __restrict__ x,
                                                  const unsigned long long* __restrict__ bmbits,
                                                  float* __restrict__ o) {
    // Each wave owns two adjacent 64-float4 chunks (2 KB contiguous per t).
    // Thread g: f0 = (g&~63)*2 + lane, f1 = f0 + 64 (float4 indices).
    // 16 chunks per plane, paired (even,odd) -> a pair never straddles a plane.
    const int HW4 = HH * WW / 4;  // 1024 float4 groups per plane
    int g = blockIdx.x * blockDim.x + threadIdx.x;  // [0, 1048576)
    int lane = g & 63;
    int f0 = ((g & ~63) << 1) + lane;  // float4 index of chunk0 element
    // f1 = f0 + 64

    int hw4 = f0 & (HW4 - 1);
    int c = (f0 >> 10) & (CHN - 1);
    int b = f0 >> 16;
    if (b >= BSZ) return;

    int h0 = hw4 >> 4;                // row of chunk0 (chunk1 row = h0+4)
    int sh = (hw4 & 15) * 4;          // same nibble shift for both chunks

    size_t xoff = (((size_t)b * CHN + c) * (size_t)(HH * WW)) + (size_t)hw4 * 4;
    const size_t XT = (size_t)BSZ * CHN * HH * WW;  // x/o time stride (floats)
    int mrow = b * HH + h0;                         // chunk1 mask row = +4
    const int MT = BSZ * HH;

    v4f ua = {0.f, 0.f, 0.f, 0.f};
    v4f ub = {0.f, 0.f, 0.f, 0.f};
#pragma unroll
    for (int t = 0; t < TSTEPS; ++t) {
        const float* xp = x + xoff + (size_t)t * XT;
        v4f xa = __builtin_nontemporal_load((const v4f*)xp);
        v4f xb = __builtin_nontemporal_load((const v4f*)(xp + 256));  // +64 float4
        unsigned int na = (unsigned int)((bmbits[mrow + t * MT] >> sh) & 0xFull);
        unsigned int nb = (unsigned int)((bmbits[mrow + 4 + t * MT] >> sh) & 0xFull);
        v4f oa, ob;
#pragma unroll
        for (int j = 0; j < 4; ++j) {
            ua[j] = (ua[j] > 1.0f ? 0.0f : 0.5f * ua[j]) + xa[j];
            oa[j] = (ua[j] > 1.0f && !(na & (1u << j))) ? 1.0f : 0.0f;
            ub[j] = (ub[j] > 1.0f ? 0.0f : 0.5f * ub[j]) + xb[j];
            ob[j] = (ub[j] > 1.0f && !(nb & (1u << j))) ? 1.0f : 0.0f;
        }
        float* op = o + xoff + (size_t)t * XT;
        __builtin_nontemporal_store(oa, (v4f*)op);
        __builtin_nontemporal_store(ob, (v4f*)(op + 256));
    }
}

extern "C" void kernel_launch(void* const* d_in, const int* in_sizes, int n_in,
                              void* d_out, int out_size, void* d_ws, size_t ws_size,
                              hipStream_t stream) {
    const float* x = (const float*)d_in[0];
    const float* mask_rand = (const float*)d_in[1];
    float* out = (float*)d_out;
    unsigned long long* bmbits = (unsigned long long*)d_ws;  // 10240 * 8 B = 80 KB

    const int bm_rows = TSTEPS * BSZ * HH;                  // 10240 rows (1 wave each)
    const int lif_threads = BSZ * CHN * (HH * WW / 4) / 2;  // 1,048,576

    bm_bits_kernel<<<bm_rows / 4, 256, 0, stream>>>(mask_rand, bmbits);
    lif_kernel<<<lif_threads / 256, 256, 0, stream>>>(x, bmbits, out);
}

// Round 9
// 274.533 us; speedup vs baseline: 1.0766x; 1.0127x over previous
//
#include <hip/hip_runtime.h>

// DropBlock + LIF forward, two kernels (R9: 4-chunk wave fattening).
// x: [T*bs, C, H, W] = [160, 64, 64, 64] f32, mask_rand: [160, 64, 64] f32
// out: [160, 64, 64, 64] f32
//
// Scoreboard: R8 (NT, 2-chunk) 278.0 BEST | R0 (NT, 1-chunk) 280.6 |
// R5 (plain) 288.9 | R1 (grid-stride) 295.1 | R4 (strided 32B/thr) 295.6.
// Lessons: NT wins; per-INSTRUCTION 1KB-solid wave footprint mandatory;
// minimal streams/thread; chunk fattening 2x gained 2.6 µs.
// R9: 4 chunks/thread (+0/+1/+2/+3 KB). 2048 blocks = 8 blocks/CU = exactly
// 32 waves/CU -> single fully-resident occupancy pass (R8's 4096 blocks
// needed 2 passes), 20 NT loads in flight/thread, 4 KB contig per stream.
//
// Stage 1 (bm_bits_kernel): per row (one wave each), dropblock row-mask as a
//   64-bit word: 7 clipped vertical loads/lane -> OR -> __ballot (vertical
//   dilate) -> bit smear +/-3 (horizontal dilate). Set bit = dropped.
// Stage 2 (lif_kernel): u = (u>1 ? 0 : 0.5u) + x_t (bitwise equal to
//   tau*u*(1-spike)+x), o_t = (u>1 && !dropped) ? 1 : 0.

#define TSTEPS 5
#define BSZ 32
#define CHN 64
#define HH 64
#define WW 64

typedef float v4f __attribute__((ext_vector_type(4)));

__global__ __launch_bounds__(256) void bm_bits_kernel(const float* __restrict__ mr,
                                                      unsigned long long* __restrict__ bmbits) {
    // one wave (64 lanes) per row; 4 waves per block; rows = T*bs*HH = 10240
    const float GAMMA = (float)(0.1 / 49.0);  // matches JAX weak-type promotion
    int row = blockIdx.x * 4 + (threadIdx.x >> 6);  // [0, 10240)
    int lane = threadIdx.x & 63;                    // pixel w
    int h = row & (HH - 1);
    int n = row >> 6;  // plane id in [0, T*bs)

    const float* base = mr + (size_t)n * (HH * WW) + lane;
    bool drop = false;
#pragma unroll
    for (int dh = -3; dh <= 3; ++dh) {
        int hh = h + dh;
        if (hh >= 0 && hh < HH) drop = drop || (base[hh * WW] < GAMMA);
    }
    unsigned long long m = __ballot(drop);  // bit w = column drop (vertical done)
    unsigned long long s = m | (m << 1) | (m << 2) | (m << 3)
                             | (m >> 1) | (m >> 2) | (m >> 3);
    if (lane == 0) bmbits[row] = s;  // set bit => dropped => output 0
}

__global__ __launch_bounds__(256) void lif_kernel(const float* __restrict__ x,
                                                  const unsigned long long* __restrict__ bmbits,
                                                  float* __restrict__ o) {
    // Each wave owns FOUR adjacent 64-float4 chunks (4 KB contiguous per t).
    // Thread g: f(k) = (g&~63)*4 + lane + k*64, k=0..3 (float4 indices).
    // 4 chunk-groups per plane (256-float4 aligned) -> never straddle a plane.
    const int HW4 = HH * WW / 4;  // 1024 float4 groups per plane
    int g = blockIdx.x * blockDim.x + threadIdx.x;  // [0, 524288)
    int lane = g & 63;
    int f0 = ((g & ~63) << 2) + lane;  // float4 index of chunk0 element

    int hw4 = f0 & (HW4 - 1);
    int c = (f0 >> 10) & (CHN - 1);
    int b = f0 >> 16;
    if (b >= BSZ) return;

    int h0 = hw4 >> 4;        // row of chunk0 (chunk k row = h0 + 4k)
    int sh = (hw4 & 15) * 4;  // same nibble shift for all chunks

    size_t xoff = (((size_t)b * CHN + c) * (size_t)(HH * WW)) + (size_t)hw4 * 4;
    const size_t XT = (size_t)BSZ * CHN * HH * WW;  // x/o time stride (floats)
    int mrow = b * HH + h0;                         // chunk k mask row = +4k
    const int MT = BSZ * HH;

    v4f u[4];
#pragma unroll
    for (int k = 0; k < 4; ++k) u[k] = (v4f){0.f, 0.f, 0.f, 0.f};

#pragma unroll
    for (int t = 0; t < TSTEPS; ++t) {
        const float* xp = x + xoff + (size_t)t * XT;
        float* op = o + xoff + (size_t)t * XT;
        unsigned long long mw0 = bmbits[mrow + 0 + t * MT];
        unsigned long long mw1 = bmbits[mrow + 4 + t * MT];
        unsigned long long mw2 = bmbits[mrow + 8 + t * MT];
        unsigned long long mw3 = bmbits[mrow + 12 + t * MT];
        unsigned int nib[4] = {(unsigned int)((mw0 >> sh) & 0xFull),
                               (unsigned int)((mw1 >> sh) & 0xFull),
                               (unsigned int)((mw2 >> sh) & 0xFull),
                               (unsigned int)((mw3 >> sh) & 0xFull)};
        v4f xv[4];
#pragma unroll
        for (int k = 0; k < 4; ++k)
            xv[k] = __builtin_nontemporal_load((const v4f*)(xp + k * 256));
#pragma unroll
        for (int k = 0; k < 4; ++k) {
            v4f ov;
#pragma unroll
            for (int j = 0; j < 4; ++j) {
                u[k][j] = (u[k][j] > 1.0f ? 0.0f : 0.5f * u[k][j]) + xv[k][j];
                ov[j] = (u[k][j] > 1.0f && !(nib[k] & (1u << j))) ? 1.0f : 0.0f;
            }
            __builtin_nontemporal_store(ov, (v4f*)(op + k * 256));
        }
    }
}

extern "C" void kernel_launch(void* const* d_in, const int* in_sizes, int n_in,
                              void* d_out, int out_size, void* d_ws, size_t ws_size,
                              hipStream_t stream) {
    const float* x = (const float*)d_in[0];
    const float* mask_rand = (const float*)d_in[1];
    float* out = (float*)d_out;
    unsigned long long* bmbits = (unsigned long long*)d_ws;  // 10240 * 8 B = 80 KB

    const int bm_rows = TSTEPS * BSZ * HH;                  // 10240 rows (1 wave each)
    const int lif_threads = BSZ * CHN * (HH * WW / 4) / 4;  // 524,288

    bm_bits_kernel<<<bm_rows / 4, 256, 0, stream>>>(mask_rand, bmbits);
    lif_kernel<<<lif_threads / 256, 256, 0, stream>>>(x, bmbits, out);
}